// Round 2
// baseline (535.108 us; speedup 1.0000x reference)
//
#include <hip/hip_runtime.h>
#include <hip/hip_bf16.h>

// Attention fwd: B=4 H=16 S=2048 D=64, fp32 in/out, softmax(QK^T/8)V
// Flash-style, bf16 MFMA (16x16x32), online softmax.
// Block = 256 threads (4 waves), each block: one (head, 64-row Q tile).
// Each wave owns 16 Q rows. KV tiles of 64 staged fp32->bf16 in LDS.

constexpr int Sdim = 2048;
constexpr int Ddim = 64;
constexpr int QBLK = 64;
constexpr int KVBLK = 64;
constexpr int NW = 4;
constexpr float LOG2E = 1.44269504f;

typedef __attribute__((ext_vector_type(8))) short short8;
typedef __attribute__((ext_vector_type(4))) float f32x4;
typedef __attribute__((ext_vector_type(4))) unsigned short ushort4v;

__device__ __forceinline__ unsigned short f2bf(float f) {
    union { float f; unsigned int u; } v; v.f = f;
    unsigned int r = v.u + 0x7FFFu + ((v.u >> 16) & 1u);   // round-to-nearest-even
    return (unsigned short)(r >> 16);
}

__global__ __launch_bounds__(256, 2)
void attn_fwd(const float* __restrict__ Qg, const float* __restrict__ Kg,
              const float* __restrict__ Vg, float* __restrict__ Og)
{
    // Swizzle convention everywhere: element (row, col) stored at col ^ ((row&7)<<3)
    __shared__ unsigned short Kt[KVBLK][Ddim];    // K tile, row-major [kv][d]
    __shared__ unsigned short Vt[Ddim][KVBLK];    // V tile transposed [d][kv]
    __shared__ unsigned short Pt[NW][16][KVBLK];  // per-wave P [q][kv]

    const int tid = threadIdx.x;
    const int w   = tid >> 6;
    const int l   = tid & 63;
    const int g   = l >> 4;     // lane group 0..3
    const int q15 = l & 15;
    const int swz = (q15 & 7) << 3;  // swizzle mask for rows == (l&15) pattern

    const size_t base = (size_t)blockIdx.y * Sdim * Ddim;
    const int q0 = blockIdx.x * QBLK;

    // ---- Q fragments (A-operand), scale 1/8 folded in (exact in bf16) ----
    short8 qf[2];
    {
        const float* qrow = Qg + base + (size_t)(q0 + w * 16 + q15) * Ddim;
#pragma unroll
        for (int kc = 0; kc < 2; ++kc) {
            float fv[8];
            *(float4*)(fv)     = *(const float4*)(qrow + kc * 32 + g * 8);
            *(float4*)(fv + 4) = *(const float4*)(qrow + kc * 32 + g * 8 + 4);
            short8 r;
#pragma unroll
            for (int j = 0; j < 8; ++j) r[j] = (short)f2bf(fv[j] * 0.125f);
            qf[kc] = r;
        }
    }

    // ---- online-softmax state + O accumulator ----
    f32x4 o[4];
    float m_run[4], l_run[4];
#pragma unroll
    for (int nt = 0; nt < 4; ++nt)
#pragma unroll
        for (int r = 0; r < 4; ++r) o[nt][r] = 0.0f;
#pragma unroll
    for (int r = 0; r < 4; ++r) { m_run[r] = -INFINITY; l_run[r] = 0.0f; }

    for (int t = 0; t < Sdim / KVBLK; ++t) {
        __syncthreads();
        // ---- stage K (row-major, swizzled) and V (transposed, swizzled) ----
        {
            const float* Ksrc = Kg + base + (size_t)t * KVBLK * Ddim;
            const float* Vsrc = Vg + base + (size_t)t * KVBLK * Ddim;
#pragma unroll
            for (int it = 0; it < 4; ++it) {
                int idx = it * 1024 + tid * 4;
                int r = idx >> 6, c = idx & 63;
                float4 kf4 = *(const float4*)(Ksrc + idx);
                ushort4v hk;
                hk.x = f2bf(kf4.x); hk.y = f2bf(kf4.y);
                hk.z = f2bf(kf4.z); hk.w = f2bf(kf4.w);
                *(ushort4v*)&Kt[r][c ^ ((r & 7) << 3)] = hk;
                float4 vf4 = *(const float4*)(Vsrc + idx);
                Vt[c + 0][r ^ (((c + 0) & 7) << 3)] = f2bf(vf4.x);
                Vt[c + 1][r ^ (((c + 1) & 7) << 3)] = f2bf(vf4.y);
                Vt[c + 2][r ^ (((c + 2) & 7) << 3)] = f2bf(vf4.z);
                Vt[c + 3][r ^ (((c + 3) & 7) << 3)] = f2bf(vf4.w);
            }
        }
        __syncthreads();

        // ---- S = Q K^T (C-layout: row q=(g*4+reg), col kv=nt*16+q15) ----
        f32x4 sa[4];
#pragma unroll
        for (int nt = 0; nt < 4; ++nt)
#pragma unroll
            for (int r = 0; r < 4; ++r) sa[nt][r] = 0.0f;
#pragma unroll
        for (int kc = 0; kc < 2; ++kc)
#pragma unroll
            for (int nt = 0; nt < 4; ++nt) {
                const short8 kf = *(const short8*)&Kt[nt * 16 + q15][(kc * 32 + g * 8) ^ swz];
                sa[nt] = __builtin_amdgcn_mfma_f32_16x16x32_bf16(qf[kc], kf, sa[nt], 0, 0, 0);
            }

        // ---- online softmax (rows are lane-group-local; reduce over q15 dim) ----
        float pv[4][4]; // [nt][r]
        float fr[4];
#pragma unroll
        for (int r = 0; r < 4; ++r) {
            float mx = fmaxf(fmaxf(sa[0][r], sa[1][r]), fmaxf(sa[2][r], sa[3][r]));
#pragma unroll
            for (int off = 1; off < 16; off <<= 1) mx = fmaxf(mx, __shfl_xor(mx, off));
            float mnew = fmaxf(m_run[r], mx);
            fr[r] = exp2f((m_run[r] - mnew) * LOG2E);
            m_run[r] = mnew;
            float s = 0.0f;
#pragma unroll
            for (int nt = 0; nt < 4; ++nt) {
                float p = exp2f((sa[nt][r] - mnew) * LOG2E);
                pv[nt][r] = p; s += p;
            }
#pragma unroll
            for (int off = 1; off < 16; off <<= 1) s += __shfl_xor(s, off);
            l_run[r] = l_run[r] * fr[r] + s;
        }
#pragma unroll
        for (int nt = 0; nt < 4; ++nt)
#pragma unroll
            for (int r = 0; r < 4; ++r) o[nt][r] *= fr[r];

        // ---- stage P through per-wave LDS (C-layout write -> A-layout read) ----
#pragma unroll
        for (int nt = 0; nt < 4; ++nt)
#pragma unroll
            for (int r = 0; r < 4; ++r) {
                int qrow = g * 4 + r;
                Pt[w][qrow][(nt * 16 + q15) ^ ((qrow & 7) << 3)] = f2bf(pv[nt][r]);
            }
        short8 pf[2];
#pragma unroll
        for (int kc = 0; kc < 2; ++kc)
            pf[kc] = *(const short8*)&Pt[w][q15][(kc * 32 + g * 8) ^ swz];

        // ---- O += P V  (B-operand from transposed V tile) ----
#pragma unroll
        for (int nt = 0; nt < 4; ++nt)
#pragma unroll
            for (int kc = 0; kc < 2; ++kc) {
                const short8 vf = *(const short8*)&Vt[nt * 16 + q15][(kc * 32 + g * 8) ^ swz];
                o[nt] = __builtin_amdgcn_mfma_f32_16x16x32_bf16(pf[kc], vf, o[nt], 0, 0, 0);
            }
    }

    // ---- epilogue: O / l_run ----
#pragma unroll
    for (int r = 0; r < 4; ++r) {
        float inv = 1.0f / l_run[r];
        float* orow = Og + base + (size_t)(q0 + w * 16 + g * 4 + r) * Ddim;
#pragma unroll
        for (int nt = 0; nt < 4; ++nt) orow[nt * 16 + q15] = o[nt][r] * inv;
    }
}

extern "C" void kernel_launch(void* const* d_in, const int* in_sizes, int n_in,
                              void* d_out, int out_size, void* d_ws, size_t ws_size,
                              hipStream_t stream) {
    const float* Q = (const float*)d_in[0];
    const float* K = (const float*)d_in[1];
    const float* V = (const float*)d_in[2];
    float* O = (float*)d_out;
    dim3 grid(Sdim / QBLK, 4 * 16);
    attn_fwd<<<grid, dim3(256), 0, stream>>>(Q, K, V, O);
}

// Round 3
// 311.099 us; speedup vs baseline: 1.7201x; 1.7201x over previous
//
#include <hip/hip_runtime.h>
#include <hip/hip_bf16.h>

// Attention fwd: B=4 H=16 S=2048 D=64, fp32 in/out, softmax(QK^T/8)V
// Swapped-operand flash attention: S^T = mfma(K, Q) so each lane holds 16
// scores of ONE q-row -> near-in-register online softmax. P repacked to bf16
// pairs (v_cvt_pk_bf16_f32) and staged via conflict-free b64 LDS writes.

constexpr int Sdim = 2048;
constexpr int Ddim = 64;
constexpr int QBLK = 64;
constexpr int KVBLK = 64;
constexpr int NW = 4;
constexpr float QSCALE = 0.125f * 1.44269504f; // 1/sqrt(64) * log2(e)

typedef __attribute__((ext_vector_type(8))) short short8;
typedef __attribute__((ext_vector_type(4))) float f32x4;
typedef __attribute__((ext_vector_type(4))) unsigned short ushort4v;
typedef __attribute__((ext_vector_type(2))) unsigned int uint2v;

__device__ __forceinline__ unsigned short f2bf(float f) {
    union { float f; unsigned int u; } v; v.f = f;
    unsigned int r = v.u + 0x7FFFu + ((v.u >> 16) & 1u);   // RNE
    return (unsigned short)(r >> 16);
}

__device__ __forceinline__ unsigned int cvt_pk_bf16(float lo, float hi) {
    unsigned int r;
    asm("v_cvt_pk_bf16_f32 %0, %1, %2" : "=v"(r) : "v"(lo), "v"(hi));
    return r;
}

__global__ __launch_bounds__(256, 4)
void attn_fwd(const float* __restrict__ Qg, const float* __restrict__ Kg,
              const float* __restrict__ Vg, float* __restrict__ Og)
{
    // Swizzle convention: element (row, col) stored at col ^ ((row&7)<<3)
    __shared__ unsigned short Kt[KVBLK][Ddim];    // K tile [kv][d]
    __shared__ unsigned short Vt[Ddim][KVBLK];    // V tile transposed [d][kv]
    __shared__ unsigned short Pt[NW][16][KVBLK];  // per-wave P [q][kv]

    const int tid = threadIdx.x;
    const int w   = tid >> 6;
    const int l   = tid & 63;
    const int g   = l >> 4;       // lane group 0..3
    const int q   = l & 15;       // this lane's q-row (and d-col for B-frags)
    const int swz = (q & 7) << 3;

    const size_t base = (size_t)blockIdx.y * Sdim * Ddim;
    const int q0 = blockIdx.x * QBLK;

    // ---- Q fragments (B-operand of swapped QK^T), scale*log2e folded ----
    short8 qf[2];
    {
        const float* qrow = Qg + base + (size_t)(q0 + w * 16 + q) * Ddim;
#pragma unroll
        for (int kc = 0; kc < 2; ++kc) {
            float fv[8];
            *(float4*)(fv)     = *(const float4*)(qrow + kc * 32 + g * 8);
            *(float4*)(fv + 4) = *(const float4*)(qrow + kc * 32 + g * 8 + 4);
            short8 r;
#pragma unroll
            for (int j = 0; j < 8; ++j) r[j] = (short)f2bf(fv[j] * QSCALE);
            qf[kc] = r;
        }
    }

    // ---- state: O acc (rows 4g+r, cols dt*16+q), per-q-row m/l (replicated over g) ----
    f32x4 o[4];
#pragma unroll
    for (int dt = 0; dt < 4; ++dt)
#pragma unroll
        for (int r = 0; r < 4; ++r) o[dt][r] = 0.0f;
    float m_run = -INFINITY, l_run = 0.0f;

    for (int t = 0; t < Sdim / KVBLK; ++t) {
        __syncthreads();
        {
            const float* Ksrc = Kg + base + (size_t)t * KVBLK * Ddim;
            const float* Vsrc = Vg + base + (size_t)t * KVBLK * Ddim;
            // K: row-major, vectorized swizzled writes
#pragma unroll
            for (int it = 0; it < 4; ++it) {
                int idx = it * 1024 + tid * 4;
                int r = idx >> 6, c = idx & 63;
                float4 kf4 = *(const float4*)(Ksrc + idx);
                ushort4v hk;
                hk.x = f2bf(kf4.x); hk.y = f2bf(kf4.y);
                hk.z = f2bf(kf4.z); hk.w = f2bf(kf4.w);
                *(ushort4v*)&Kt[r][c ^ ((r & 7) << 3)] = hk;
            }
            // V: transpose via column-per-lane: wave w stages kv rows [16w,16w+16),
            // lane = d. Coalesced scalar global reads, b64 swizzled writes.
            {
                const int d = l;
                const int vswz = (d & 7) << 3;
#pragma unroll
                for (int i = 0; i < 4; ++i) {
                    int kv0 = w * 16 + i * 4;
                    float a0 = Vsrc[(size_t)(kv0 + 0) * Ddim + d];
                    float a1 = Vsrc[(size_t)(kv0 + 1) * Ddim + d];
                    float a2 = Vsrc[(size_t)(kv0 + 2) * Ddim + d];
                    float a3 = Vsrc[(size_t)(kv0 + 3) * Ddim + d];
                    ushort4v hv;
                    hv.x = f2bf(a0); hv.y = f2bf(a1);
                    hv.z = f2bf(a2); hv.w = f2bf(a3);
                    *(ushort4v*)&Vt[d][kv0 ^ vswz] = hv;
                }
            }
        }
        __syncthreads();

        // ---- S^T = mfma(K, Q): lane holds S[q][kv=16nt+4g+r] (log2-domain) ----
        f32x4 sa[4];
#pragma unroll
        for (int nt = 0; nt < 4; ++nt)
#pragma unroll
            for (int r = 0; r < 4; ++r) sa[nt][r] = 0.0f;
#pragma unroll
        for (int kc = 0; kc < 2; ++kc)
#pragma unroll
            for (int nt = 0; nt < 4; ++nt) {
                const short8 kf = *(const short8*)&Kt[nt * 16 + q][(kc * 32 + g * 8) ^ swz];
                sa[nt] = __builtin_amdgcn_mfma_f32_16x16x32_bf16(kf, qf[kc], sa[nt], 0, 0, 0);
            }

        // ---- online softmax: 15 in-lane + 2 shfl per reduce ----
        float mx = sa[0][0];
#pragma unroll
        for (int nt = 0; nt < 4; ++nt)
#pragma unroll
            for (int r = 0; r < 4; ++r) mx = fmaxf(mx, sa[nt][r]);
        mx = fmaxf(mx, __shfl_xor(mx, 16));
        mx = fmaxf(mx, __shfl_xor(mx, 32));
        float mnew = fmaxf(m_run, mx);
        float fr = exp2f(m_run - mnew);
        m_run = mnew;

        float p[4][4];
        float s = 0.0f;
#pragma unroll
        for (int nt = 0; nt < 4; ++nt)
#pragma unroll
            for (int r = 0; r < 4; ++r) {
                float e = exp2f(sa[nt][r] - mnew);
                p[nt][r] = e; s += e;
            }
        s += __shfl_xor(s, 16);
        s += __shfl_xor(s, 32);
        l_run = l_run * fr + s;

        // ---- P -> bf16 pairs -> conflict-free b64 LDS writes (per-wave tile) ----
#pragma unroll
        for (int nt = 0; nt < 4; ++nt) {
            uint2v pp;
            pp.x = cvt_pk_bf16(p[nt][0], p[nt][1]);   // kv = 16nt+4g+{0,1}
            pp.y = cvt_pk_bf16(p[nt][2], p[nt][3]);   // kv = 16nt+4g+{2,3}
            *(uint2v*)&Pt[w][q][(nt * 16 + 4 * g) ^ swz] = pp;
        }

        // ---- rescale O by fr of its own row (4g+r) ----
        float frb[4];
#pragma unroll
        for (int r = 0; r < 4; ++r) frb[r] = __shfl(fr, 4 * g + r);
#pragma unroll
        for (int dt = 0; dt < 4; ++dt)
#pragma unroll
            for (int r = 0; r < 4; ++r) o[dt][r] *= frb[r];

        // ---- O += P V ----
#pragma unroll
        for (int kc = 0; kc < 2; ++kc) {
            const short8 pa = *(const short8*)&Pt[w][q][(kc * 32 + g * 8) ^ swz];
#pragma unroll
            for (int dt = 0; dt < 4; ++dt) {
                const short8 vf = *(const short8*)&Vt[dt * 16 + q][(kc * 32 + g * 8) ^ swz];
                o[dt] = __builtin_amdgcn_mfma_f32_16x16x32_bf16(pa, vf, o[dt], 0, 0, 0);
            }
        }
    }

    // ---- epilogue: divide by l of row 4g+r, store ----
    float inv = 1.0f / l_run;
    float invb[4];
#pragma unroll
    for (int r = 0; r < 4; ++r) invb[r] = __shfl(inv, 4 * g + r);
#pragma unroll
    for (int r = 0; r < 4; ++r) {
        float* orow = Og + base + (size_t)(q0 + w * 16 + 4 * g + r) * Ddim;
#pragma unroll
        for (int dt = 0; dt < 4; ++dt) orow[dt * 16 + q] = o[dt][r] * invb[r];
    }
}

extern "C" void kernel_launch(void* const* d_in, const int* in_sizes, int n_in,
                              void* d_out, int out_size, void* d_ws, size_t ws_size,
                              hipStream_t stream) {
    const float* Q = (const float*)d_in[0];
    const float* K = (const float*)d_in[1];
    const float* V = (const float*)d_in[2];
    float* O = (float*)d_out;
    dim3 grid(Sdim / QBLK, 4 * 16);
    attn_fwd<<<grid, dim3(256), 0, stream>>>(Q, K, V, O);
}

// Round 5
// 257.293 us; speedup vs baseline: 2.0798x; 1.2091x over previous
//
#include <hip/hip_runtime.h>
#include <hip/hip_bf16.h>

// Attention fwd: B=4 H=16 S=2048 D=64, fp32 in/out, softmax(QK^T/8)V
// Round 4: pre-pass converts K (tile-ready swizzled bf16) and V (transposed
// swizzled bf16) ONCE into d_ws; main kernel stages via global_load_lds
// (zero-VALU staging). Swapped-operand QK^T, in-register online softmax,
// defer-max (T13), setprio around MFMA (T5).

constexpr int Sdim = 2048;
constexpr int Ddim = 64;
constexpr int QBLK = 64;
constexpr int KVBLK = 64;
constexpr int NW = 4;
constexpr int NBH = 64;             // B*H
constexpr int NT = Sdim / KVBLK;    // 32
constexpr float QSCALE = 0.125f * 1.44269504f; // 1/sqrt(64) * log2(e)
constexpr float DEFER_THR = 11.0f;  // log2 units: p <= 2^11, safe in bf16/fp32

typedef __attribute__((ext_vector_type(8))) short short8;
typedef __attribute__((ext_vector_type(4))) float f32x4;
typedef __attribute__((ext_vector_type(4))) unsigned short ushort4v;
typedef __attribute__((ext_vector_type(2))) unsigned int uint2v;

typedef __attribute__((address_space(1))) const unsigned int GU32;
typedef __attribute__((address_space(3))) unsigned int LU32;

__device__ __forceinline__ unsigned short f2bf(float f) {
    union { float f; unsigned int u; } v; v.f = f;
    unsigned int r = v.u + 0x7FFFu + ((v.u >> 16) & 1u);   // RNE
    return (unsigned short)(r >> 16);
}

__device__ __forceinline__ unsigned int cvt_pk_bf16(float lo, float hi) {
    unsigned int r;
    asm("v_cvt_pk_bf16_f32 %0, %1, %2" : "=v"(r) : "v"(lo), "v"(hi));
    return r;
}

__device__ __forceinline__ void gload_lds16(const unsigned short* g, unsigned short* l) {
    __builtin_amdgcn_global_load_lds((GU32*)g, (LU32*)l, 16, 0, 0);
}

// ---- pre-pass: K -> bf16, swizzled within each row: elem (s, c) at c ^ ((s&7)<<3)
__global__ __launch_bounds__(256)
void prep_k(const float* __restrict__ Kg, unsigned short* __restrict__ Kbf) {
    size_t idx = ((size_t)blockIdx.x * 256 + threadIdx.x) * 4;
    int c0 = (int)(idx & 63);
    size_t row = idx >> 6;
    int swz = ((int)row & 7) << 3;
    float4 f = *(const float4*)(Kg + idx);
    ushort4v h;
    h.x = f2bf(f.x); h.y = f2bf(f.y); h.z = f2bf(f.z); h.w = f2bf(f.w);
    *(ushort4v*)(Kbf + (row << 6) + (c0 ^ swz)) = h;
}

// ---- pre-pass: V -> bf16 transposed per 64-row tile: Vt[d][kv ^ ((d&7)<<3)]
__global__ __launch_bounds__(256)
void prep_v(const float* __restrict__ Vg, unsigned short* __restrict__ Vtb) {
    int bh = blockIdx.x >> 5, t = blockIdx.x & 31;
    const float* src = Vg + ((size_t)bh * Sdim + t * KVBLK) * Ddim;
    unsigned short* dst = Vtb + ((size_t)bh * NT + t) * (Ddim * KVBLK);
    int kv0 = (threadIdx.x & 15) * 4;
    int d0  = (threadIdx.x >> 4) * 4;
    float v[4][4];
#pragma unroll
    for (int j = 0; j < 4; ++j)
        *(float4*)v[j] = *(const float4*)(src + (size_t)(kv0 + j) * Ddim + d0);
#pragma unroll
    for (int i = 0; i < 4; ++i) {
        int d = d0 + i;
        ushort4v h;
        h.x = f2bf(v[0][i]); h.y = f2bf(v[1][i]);
        h.z = f2bf(v[2][i]); h.w = f2bf(v[3][i]);
        *(ushort4v*)(dst + d * KVBLK + (kv0 ^ ((d & 7) << 3))) = h;
    }
}

// ================= fast main kernel =================
__global__ __launch_bounds__(256, 4)
void attn_fwd_fast(const float* __restrict__ Qg, const unsigned short* __restrict__ Kbf,
                   const unsigned short* __restrict__ Vtb, float* __restrict__ Og)
{
    __shared__ unsigned short Kt[KVBLK][Ddim];    // [kv][d], swizzled
    __shared__ unsigned short Vt[Ddim][KVBLK];    // [d][kv], swizzled
    __shared__ unsigned short Pt[NW][16][KVBLK];  // per-wave P [q][kv], swizzled

    const int tid = threadIdx.x;
    const int w   = tid >> 6;
    const int l   = tid & 63;
    const int g   = l >> 4;
    const int q   = l & 15;
    const int swz = (q & 7) << 3;

    const int bh = blockIdx.y;
    const size_t base = (size_t)bh * Sdim * Ddim;
    const int q0 = blockIdx.x * QBLK;

    // Q fragments (B-operand of swapped QK^T), scale*log2e folded in
    short8 qf[2];
    {
        const float* qrow = Qg + base + (size_t)(q0 + w * 16 + q) * Ddim;
#pragma unroll
        for (int kc = 0; kc < 2; ++kc) {
            float fv[8];
            *(float4*)(fv)     = *(const float4*)(qrow + kc * 32 + g * 8);
            *(float4*)(fv + 4) = *(const float4*)(qrow + kc * 32 + g * 8 + 4);
            short8 r;
#pragma unroll
            for (int j = 0; j < 8; ++j) r[j] = (short)f2bf(fv[j] * QSCALE);
            qf[kc] = r;
        }
    }

    f32x4 o[4];
#pragma unroll
    for (int dt = 0; dt < 4; ++dt)
#pragma unroll
        for (int r = 0; r < 4; ++r) o[dt][r] = 0.0f;
    float m_run = -INFINITY, l_run = 0.0f;

    for (int t = 0; t < NT; ++t) {
        __syncthreads();
        {
            // zero-VALU staging: linear LDS dest, pre-swizzled global source
            const unsigned short* ksrc = Kbf + base + (size_t)t * (KVBLK * Ddim);
            const unsigned short* vsrc = Vtb + base + (size_t)t * (KVBLK * Ddim);
            const int eo = w * 512 + l * 8;   // elements
            gload_lds16(ksrc + eo,        &Kt[0][0] + w * 512);
            gload_lds16(ksrc + eo + 2048, &Kt[0][0] + w * 512 + 2048);
            gload_lds16(vsrc + eo,        &Vt[0][0] + w * 512);
            gload_lds16(vsrc + eo + 2048, &Vt[0][0] + w * 512 + 2048);
        }
        __syncthreads();

        // S^T = mfma(K, Q): lane holds S[q][kv = 16nt+4g+r], log2-domain
        f32x4 sa[4];
#pragma unroll
        for (int nt = 0; nt < 4; ++nt)
#pragma unroll
            for (int r = 0; r < 4; ++r) sa[nt][r] = 0.0f;
        __builtin_amdgcn_s_setprio(1);
#pragma unroll
        for (int kc = 0; kc < 2; ++kc)
#pragma unroll
            for (int nt = 0; nt < 4; ++nt) {
                const short8 kf = *(const short8*)&Kt[nt * 16 + q][(kc * 32 + g * 8) ^ swz];
                sa[nt] = __builtin_amdgcn_mfma_f32_16x16x32_bf16(kf, qf[kc], sa[nt], 0, 0, 0);
            }
        __builtin_amdgcn_s_setprio(0);

        // online softmax, defer-max (T13)
        float mx = sa[0][0];
#pragma unroll
        for (int nt = 0; nt < 4; ++nt)
#pragma unroll
            for (int r = 0; r < 4; ++r) mx = fmaxf(mx, sa[nt][r]);
        mx = fmaxf(mx, __shfl_xor(mx, 16));
        mx = fmaxf(mx, __shfl_xor(mx, 32));

        float p[4][4];
        float s = 0.0f;
        if (__all(mx - m_run <= DEFER_THR)) {
            // max didn't grow enough: keep m_run, no O-rescale
#pragma unroll
            for (int nt = 0; nt < 4; ++nt)
#pragma unroll
                for (int r = 0; r < 4; ++r) {
                    float e = exp2f(sa[nt][r] - m_run);
                    p[nt][r] = e; s += e;
                }
            s += __shfl_xor(s, 16);
            s += __shfl_xor(s, 32);
            l_run += s;
        } else {
            float mnew = fmaxf(m_run, mx);
            float fr = exp2f(m_run - mnew);
            m_run = mnew;
#pragma unroll
            for (int nt = 0; nt < 4; ++nt)
#pragma unroll
                for (int r = 0; r < 4; ++r) {
                    float e = exp2f(sa[nt][r] - mnew);
                    p[nt][r] = e; s += e;
                }
            s += __shfl_xor(s, 16);
            s += __shfl_xor(s, 32);
            l_run = l_run * fr + s;
            float frb[4];
#pragma unroll
            for (int r = 0; r < 4; ++r) frb[r] = __shfl(fr, 4 * g + r);
#pragma unroll
            for (int dt = 0; dt < 4; ++dt)
#pragma unroll
                for (int r = 0; r < 4; ++r) o[dt][r] *= frb[r];
        }

        // P -> bf16 pairs -> conflict-free b64 LDS writes
#pragma unroll
        for (int nt = 0; nt < 4; ++nt) {
            uint2v pp;
            pp.x = cvt_pk_bf16(p[nt][0], p[nt][1]);
            pp.y = cvt_pk_bf16(p[nt][2], p[nt][3]);
            *(uint2v*)&Pt[w][q][(nt * 16 + 4 * g) ^ swz] = pp;
        }

        // O += P V
        __builtin_amdgcn_s_setprio(1);
#pragma unroll
        for (int kc = 0; kc < 2; ++kc) {
            const short8 pa = *(const short8*)&Pt[w][q][(kc * 32 + g * 8) ^ swz];
#pragma unroll
            for (int dt = 0; dt < 4; ++dt) {
                const short8 vf = *(const short8*)&Vt[dt * 16 + q][(kc * 32 + g * 8) ^ swz];
                o[dt] = __builtin_amdgcn_mfma_f32_16x16x32_bf16(pa, vf, o[dt], 0, 0, 0);
            }
        }
        __builtin_amdgcn_s_setprio(0);
    }

    float inv = 1.0f / l_run;
    float invb[4];
#pragma unroll
    for (int r = 0; r < 4; ++r) invb[r] = __shfl(inv, 4 * g + r);
#pragma unroll
    for (int r = 0; r < 4; ++r) {
        float* orow = Og + base + (size_t)(q0 + w * 16 + 4 * g + r) * Ddim;
#pragma unroll
        for (int dt = 0; dt < 4; ++dt) orow[dt * 16 + q] = o[dt][r] * invb[r];
    }
}

// ================= fallback (round-3 kernel, proven) =================
__global__ __launch_bounds__(256, 4)
void attn_fwd_slow(const float* __restrict__ Qg, const float* __restrict__ Kg,
                   const float* __restrict__ Vg, float* __restrict__ Og)
{
    __shared__ unsigned short Kt[KVBLK][Ddim];
    __shared__ unsigned short Vt[Ddim][KVBLK];
    __shared__ unsigned short Pt[NW][16][KVBLK];

    const int tid = threadIdx.x;
    const int w   = tid >> 6;
    const int l   = tid & 63;
    const int g   = l >> 4;
    const int q   = l & 15;
    const int swz = (q & 7) << 3;

    const size_t base = (size_t)blockIdx.y * Sdim * Ddim;
    const int q0 = blockIdx.x * QBLK;

    short8 qf[2];
    {
        const float* qrow = Qg + base + (size_t)(q0 + w * 16 + q) * Ddim;
#pragma unroll
        for (int kc = 0; kc < 2; ++kc) {
            float fv[8];
            *(float4*)(fv)     = *(const float4*)(qrow + kc * 32 + g * 8);
            *(float4*)(fv + 4) = *(const float4*)(qrow + kc * 32 + g * 8 + 4);
            short8 r;
#pragma unroll
            for (int j = 0; j < 8; ++j) r[j] = (short)f2bf(fv[j] * QSCALE);
            qf[kc] = r;
        }
    }

    f32x4 o[4];
#pragma unroll
    for (int dt = 0; dt < 4; ++dt)
#pragma unroll
        for (int r = 0; r < 4; ++r) o[dt][r] = 0.0f;
    float m_run = -INFINITY, l_run = 0.0f;

    for (int t = 0; t < NT; ++t) {
        __syncthreads();
        {
            const float* Ksrc = Kg + base + (size_t)t * KVBLK * Ddim;
            const float* Vsrc = Vg + base + (size_t)t * KVBLK * Ddim;
#pragma unroll
            for (int it = 0; it < 4; ++it) {
                int idx = it * 1024 + tid * 4;
                int r = idx >> 6, c = idx & 63;
                float4 kf4 = *(const float4*)(Ksrc + idx);
                ushort4v hk;
                hk.x = f2bf(kf4.x); hk.y = f2bf(kf4.y);
                hk.z = f2bf(kf4.z); hk.w = f2bf(kf4.w);
                *(ushort4v*)&Kt[r][c ^ ((r & 7) << 3)] = hk;
            }
            {
                const int d = l;
                const int vswz = (d & 7) << 3;
#pragma unroll
                for (int i = 0; i < 4; ++i) {
                    int kv0 = w * 16 + i * 4;
                    float a0 = Vsrc[(size_t)(kv0 + 0) * Ddim + d];
                    float a1 = Vsrc[(size_t)(kv0 + 1) * Ddim + d];
                    float a2 = Vsrc[(size_t)(kv0 + 2) * Ddim + d];
                    float a3 = Vsrc[(size_t)(kv0 + 3) * Ddim + d];
                    ushort4v hv;
                    hv.x = f2bf(a0); hv.y = f2bf(a1);
                    hv.z = f2bf(a2); hv.w = f2bf(a3);
                    *(ushort4v*)&Vt[d][kv0 ^ vswz] = hv;
                }
            }
        }
        __syncthreads();

        f32x4 sa[4];
#pragma unroll
        for (int nt = 0; nt < 4; ++nt)
#pragma unroll
            for (int r = 0; r < 4; ++r) sa[nt][r] = 0.0f;
#pragma unroll
        for (int kc = 0; kc < 2; ++kc)
#pragma unroll
            for (int nt = 0; nt < 4; ++nt) {
                const short8 kf = *(const short8*)&Kt[nt * 16 + q][(kc * 32 + g * 8) ^ swz];
                sa[nt] = __builtin_amdgcn_mfma_f32_16x16x32_bf16(kf, qf[kc], sa[nt], 0, 0, 0);
            }

        float mx = sa[0][0];
#pragma unroll
        for (int nt = 0; nt < 4; ++nt)
#pragma unroll
            for (int r = 0; r < 4; ++r) mx = fmaxf(mx, sa[nt][r]);
        mx = fmaxf(mx, __shfl_xor(mx, 16));
        mx = fmaxf(mx, __shfl_xor(mx, 32));
        float mnew = fmaxf(m_run, mx);
        float fr = exp2f(m_run - mnew);
        m_run = mnew;

        float p[4][4];
        float s = 0.0f;
#pragma unroll
        for (int nt = 0; nt < 4; ++nt)
#pragma unroll
            for (int r = 0; r < 4; ++r) {
                float e = exp2f(sa[nt][r] - mnew);
                p[nt][r] = e; s += e;
            }
        s += __shfl_xor(s, 16);
        s += __shfl_xor(s, 32);
        l_run = l_run * fr + s;

#pragma unroll
        for (int nt = 0; nt < 4; ++nt) {
            uint2v pp;
            pp.x = cvt_pk_bf16(p[nt][0], p[nt][1]);
            pp.y = cvt_pk_bf16(p[nt][2], p[nt][3]);
            *(uint2v*)&Pt[w][q][(nt * 16 + 4 * g) ^ swz] = pp;
        }

        float frb[4];
#pragma unroll
        for (int r = 0; r < 4; ++r) frb[r] = __shfl(fr, 4 * g + r);
#pragma unroll
        for (int dt = 0; dt < 4; ++dt)
#pragma unroll
            for (int r = 0; r < 4; ++r) o[dt][r] *= frb[r];

#pragma unroll
        for (int kc = 0; kc < 2; ++kc) {
            const short8 pa = *(const short8*)&Pt[w][q][(kc * 32 + g * 8) ^ swz];
#pragma unroll
            for (int dt = 0; dt < 4; ++dt) {
                const short8 vf = *(const short8*)&Vt[dt * 16 + q][(kc * 32 + g * 8) ^ swz];
                o[dt] = __builtin_amdgcn_mfma_f32_16x16x32_bf16(pa, vf, o[dt], 0, 0, 0);
            }
        }
    }

    float inv = 1.0f / l_run;
    float invb[4];
#pragma unroll
    for (int r = 0; r < 4; ++r) invb[r] = __shfl(inv, 4 * g + r);
#pragma unroll
    for (int r = 0; r < 4; ++r) {
        float* orow = Og + base + (size_t)(q0 + w * 16 + 4 * g + r) * Ddim;
#pragma unroll
        for (int dt = 0; dt < 4; ++dt) orow[dt * 16 + q] = o[dt][r] * invb[r];
    }
}

extern "C" void kernel_launch(void* const* d_in, const int* in_sizes, int n_in,
                              void* d_out, int out_size, void* d_ws, size_t ws_size,
                              hipStream_t stream) {
    const float* Q = (const float*)d_in[0];
    const float* K = (const float*)d_in[1];
    const float* V = (const float*)d_in[2];
    float* O = (float*)d_out;
    const size_t elems = (size_t)NBH * Sdim * Ddim;          // 8.39M
    const size_t need  = elems * 2 * 2;                      // Kbf + Vtb, bf16
    dim3 grid(Sdim / QBLK, NBH);
    if (ws_size >= need) {
        unsigned short* Kbf = (unsigned short*)d_ws;
        unsigned short* Vtb = Kbf + elems;
        prep_k<<<dim3((unsigned)(elems / 4 / 256)), dim3(256), 0, stream>>>(K, Kbf);
        prep_v<<<dim3(NBH * NT), dim3(256), 0, stream>>>(V, Vtb);
        attn_fwd_fast<<<grid, dim3(256), 0, stream>>>(Q, Kbf, Vtb, O);
    } else {
        attn_fwd_slow<<<grid, dim3(256), 0, stream>>>(Q, K, V, O);
    }
}